// Round 1
// baseline (3286.317 us; speedup 1.0000x reference)
//
#include <hip/hip_runtime.h>
#include <stdint.h>

// ---------------------------------------------------------------------------
// 2-layer LSTM (B=256, T=512, D_IN=64, H=512) + FC head, MI355X/gfx950.
// Round 16 = r15 + SPLIT-FLAG latency pipelining.
//   r15 serialized 3 LLC RTTs per epoch (poll, tile-load drain, publish
//   drain) in one chain.  This round splits the Y (ys0) and H (h1) flag
//   lines so each RTT overlaps compute that does not depend on it:
//   - flagY is set MID-epoch (after the ys0 publish drain); consumers poll
//     Y and issue the G-load at the TAIL of the previous epoch -> at epoch
//     top the ys0 tile is already in registers (kills top-of-epoch RTT).
//   - pollH+issueH sit between phase-1 and combine0; H-load RTT hides
//     under combine0+publish, one shared drain.
//   - pollY+issueG (next epoch) sit between phase-2 and combine1; G-load
//     RTT hides under combine1+publish+xproj, one shared drain that also
//     covers the h1 publish.
//   Release/acquire unchanged: every flag only after own vm_drain; polls
//   order every publish behind all consumers' reads of the slot reused.
//   Cost: 3 barriers/epoch (was 2) -- hbufH now staged mid-epoch.
// Memory pattern byte-identical to r10/r15 (WG-coop 64B/lane staged loads,
// shuffle-gather publish).  Exchange primitives r6/r8/r10-proven.
// ---------------------------------------------------------------------------

typedef __bf16 bf16;
typedef bf16  bf16x8 __attribute__((ext_vector_type(8)));
typedef float f32x4  __attribute__((ext_vector_type(4)));
typedef unsigned int u32;
typedef unsigned long long u64;

#define NB   256
#define NT   512
#define NDIN 64
#define NH   512
#define POLL_GUARD (1 << 20)
#define SLOT_BYTES ((size_t)NB * NH * 2)          // 262144

// workspace layout (bytes)
static constexpr size_t OFF_XB   = 0;                                  // [B][T][64] bf16
static constexpr size_t OFF_WB0  = OFF_XB  + (size_t)NB*NT*NDIN*2;     // Whh0 bf16 [2048][512]
static constexpr size_t OFF_WI0  = OFF_WB0 + (size_t)2048*512*2;       // Wih0 bf16 [2048][64]
static constexpr size_t OFF_WI1  = OFF_WI0 + (size_t)2048*64*2;        // Wih1 bf16 [2048][512]
static constexpr size_t OFF_WHS1 = OFF_WI1 + (size_t)2048*512*2;       // Whh1 swizzled slices
static constexpr size_t OFF_Y0R  = OFF_WHS1+ (size_t)16*128*512*2;     // ys0 ring [2][B][H] bf16
static constexpr size_t OFF_R1   = OFF_Y0R + 2*SLOT_BYTES;             // h1  ring [2][B][H] bf16
static constexpr size_t OFF_HT   = OFF_R1  + 2*SLOT_BYTES;             // [B][H] f32
static constexpr size_t OFF_FLG  = OFF_HT  + (size_t)NB*NH*4;          // u32: Y line 64K + H line 64K
static constexpr size_t WS_NEED  = OFF_FLG + 131072;

#define MFMA16(a,b,c) __builtin_amdgcn_mfma_f32_16x16x32_bf16(a,b,c,0,0,0)

__device__ __forceinline__ float fsigm(float x) {
    return __builtin_amdgcn_rcpf(1.0f + __builtin_amdgcn_exp2f(x * -1.442695041f));
}
__device__ __forceinline__ float ftanh(float x) {
    return 1.0f - 2.0f * __builtin_amdgcn_rcpf(1.0f + __builtin_amdgcn_exp2f(x * 2.885390082f));
}
__device__ __forceinline__ u32 pack_bf16(float a, float b) {
    union { bf16 h[2]; u32 u; } un;
    un.h[0] = (bf16)a; un.h[1] = (bf16)b;
    return un.u;
}
__device__ __forceinline__ bf16x8 asf(int4 x) {
    union { int4 i; bf16x8 v; } u; u.i = x; return u.v;
}

// --- IC-coherent (sc0 sc1) batched exchange ops [proven r6/r8/r10] ---------
__device__ __forceinline__ void ld4_issue(const void* p0, const void* p1,
                                          const void* p2, const void* p3,
                                          int4& a, int4& b, int4& c, int4& d) {
    asm volatile(
        "global_load_dwordx4 %0, %4, off sc0 sc1\n\t"
        "global_load_dwordx4 %1, %5, off sc0 sc1\n\t"
        "global_load_dwordx4 %2, %6, off sc0 sc1\n\t"
        "global_load_dwordx4 %3, %7, off sc0 sc1"
        : "=&v"(a), "=&v"(b), "=&v"(c), "=&v"(d)
        : "v"(p0), "v"(p1), "v"(p2), "v"(p3)
        : "memory");
}
__device__ __forceinline__ void st64_cohr(void* p, u64 v) {
    asm volatile("global_store_dwordx2 %0, %1, off sc0 sc1" :: "v"(p), "v"(v) : "memory");
}
__device__ __forceinline__ void vm_drain() {      // rule #18: sched fence after waitcnt
    asm volatile("s_waitcnt vmcnt(0)" ::: "memory");
    __builtin_amdgcn_sched_barrier(0);
}
__device__ __forceinline__ void ld_fence() {
    asm volatile("" ::: "memory");
    __builtin_amdgcn_sched_barrier(0);
}
__device__ __forceinline__ void poll64(const u32* f, u32 target) {
    int guard = 0;
    while (__hip_atomic_load(f, __ATOMIC_RELAXED, __HIP_MEMORY_SCOPE_AGENT) < target)
        if (++guard > POLL_GUARD) break;   // wrong answer beats a hard hang
}
__device__ __forceinline__ void ast32(u32* p, u32 v) {
    __hip_atomic_store(p, v, __ATOMIC_RELAXED, __HIP_MEMORY_SCOPE_AGENT);
}

// W_hh1 LDS swizzle slot for local row lr [proven r8/r10]
__device__ __forceinline__ int wslot(int lr) {
    return ((lr >> 5) & 3) | (((lr >> 1) & 3) << 2);
}

// ---------------------------------------------------------------------------
__global__ void xcvt_kernel(const float* __restrict__ x, char* __restrict__ ws) {
    size_t i = ((size_t)blockIdx.x * 256 + threadIdx.x) * 8;
    float4 a = *(const float4*)(x + i);
    float4 b = *(const float4*)(x + i + 4);
    u32 p0 = pack_bf16(a.x, a.y), p1 = pack_bf16(a.z, a.w);
    u32 p2 = pack_bf16(b.x, b.y), p3 = pack_bf16(b.z, b.w);
    *(int4*)(ws + OFF_XB + i * 2) = make_int4((int)p0, (int)p1, (int)p2, (int)p3);
}

__global__ void prep_kernel(const float* __restrict__ Wih0f, const float* __restrict__ Whh0f,
                            const float* __restrict__ Wih1f, const float* __restrict__ Whh1f,
                            char* __restrict__ ws) {
    int idx = blockIdx.x * 256 + threadIdx.x;       // 0 .. 1048575
    ((bf16*)(ws + OFF_WB0))[idx] = (bf16)Whh0f[idx];
    ((bf16*)(ws + OFF_WI1))[idx] = (bf16)Wih1f[idx];
    if (idx < 2048 * 64) ((bf16*)(ws + OFF_WI0))[idx] = (bf16)Wih0f[idx];
    int slice = idx >> 16;
    int lr    = (idx >> 9) & 127;
    int k     = idx & 511;
    int grow  = (lr >> 5) * 512 + slice * 32 + (lr & 31);
    ((bf16*)(ws + OFF_WHS1))[(size_t)slice * 65536 + lr * 512 + (k ^ (wslot(lr) << 3))] =
        (bf16)Whh1f[(size_t)grow * 512 + k];
}

// ---------------------------------------------------------------------------
// fused dual-layer LSTM: split-flag pipelined schedule (r16)
// ---------------------------------------------------------------------------
__global__ __attribute__((amdgpu_waves_per_eu(1, 1))) __launch_bounds__(256)
void lstm_fused(const float* __restrict__ b0, const float* __restrict__ b1,
                char* __restrict__ ws) {
    extern __shared__ char smem[];
    char* WhLds = smem;                // 131072: W_hh1 slice (read-only in loop)
    char* hbufY = smem + 131072;       // 16384: ys0[e-1] tile
    char* hbufH = smem + 147456;       // 16384: h1[e-2] tile

    const int tid = threadIdx.x;
    const int v = tid >> 6, l = tid & 63;
    const int l15 = l & 15, lhi = l >> 4, g = l & 3, csel = l15 >> 2;
    const int group = blockIdx.x >> 4, htile = blockIdx.x & 15;
    const int b0r = group * 16, hs = htile * 32;

    const bf16* xb = (const bf16*)(ws + OFF_XB);
    char* y0r = ws + OFF_Y0R;
    char* r1  = ws + OFF_R1;
    float* hT = (float*)(ws + OFF_HT);
    u32* FL = (u32*)(ws + OFF_FLG);
    const u32* myLineY = FL + ((size_t)group * 16 + htile) * 64;      // lane polls +l
    const u32* myLineH = myLineY + 16384;                             // +64KiB (u32s)
    u32* peerFY       = FL + (size_t)group * 1024 + htile * 4 + v;    // + cons*64
    u32* peerFH       = peerFY + 16384;

    // stage pre-swizzled W_hh1 slice -> LDS (written once; read-only in loop)
    {
        const char* wsrc = ws + OFF_WHS1 + (size_t)htile * 131072;
#pragma unroll
        for (int i = 0; i < 32; ++i) {
            int off = (tid + i * 256) * 16;
            *(int4*)(WhLds + off) = *(const int4*)(wsrc + off);
        }
    }

    // lane -> output mapping (r8/r10): col n=l15 -> gate n&3, unit 8v+2*(n>>2)(+1)
    const int wrow0 = g * 512 + hs + 8 * v + 2 * csel;
    const int wrow1 = wrow0 + 1;

    const bf16* wb0p = (const bf16*)(ws + OFF_WB0);
    const bf16* wi0p = (const bf16*)(ws + OFF_WI0);
    const bf16* wi1p = (const bf16*)(ws + OFF_WI1);
    int4 wb0[16][2], wib1[16][2];
#pragma unroll
    for (int kk = 0; kk < 16; ++kk) {
        wb0[kk][0]  = *(const int4*)(wb0p + (size_t)wrow0 * NH + kk * 32 + lhi * 8);
        wb0[kk][1]  = *(const int4*)(wb0p + (size_t)wrow1 * NH + kk * 32 + lhi * 8);
        wib1[kk][0] = *(const int4*)(wi1p + (size_t)wrow0 * NH + kk * 32 + lhi * 8);
        wib1[kk][1] = *(const int4*)(wi1p + (size_t)wrow1 * NH + kk * 32 + lhi * 8);
    }
    int4 wib0[2][2];
#pragma unroll
    for (int kk = 0; kk < 2; ++kk) {
        wib0[kk][0] = *(const int4*)(wi0p + (size_t)wrow0 * NDIN + kk * 32 + lhi * 8);
        wib0[kk][1] = *(const int4*)(wi0p + (size_t)wrow1 * NDIN + kk * 32 + lhi * 8);
    }
    const float b00 = b0[wrow0], b01 = b0[wrow1];
    const float b10 = b1[wrow0], b11 = b1[wrow1];

    float cA0[4] = {0,0,0,0}, cA1[4] = {0,0,0,0};
    float cB0[4] = {0,0,0,0}, cB1[4] = {0,0,0,0};
    f32x4 aL00, aL01, aL10, aL11;
    const int qb = l & 60;
    const int srcl = csel * 16 + g;
    const int swz = (l15 & 7) << 4;
    const int lr0 = g * 32 + 8 * v + 2 * csel;
    const int wsw = wslot(lr0) << 4;
    const int r0 = tid >> 6;
    const int bc = (tid & 63) * 16;

    int4 G0, G1, G2, G3;               // staged ys0 tile (prefetched at prev tail)
    int4 H0, H1, H2, H3;               // staged h1 tile (fetched mid-epoch)

    auto issueG = [&](int slot) {
        const char* p = y0r + (size_t)slot * SLOT_BYTES + (size_t)b0r * 1024
                      + (size_t)r0 * 1024 + bc;
        ld4_issue(p, p + 4096, p + 8192, p + 12288, G0, G1, G2, G3);
    };
    auto issueH = [&](int slot) {
        const char* p = r1 + (size_t)slot * SLOT_BYTES + (size_t)b0r * 1024
                      + (size_t)r0 * 1024 + bc;
        ld4_issue(p, p + 4096, p + 8192, p + 12288, H0, H1, H2, H3);
    };
    auto ldsWrite = [&](char* buf, int4 A, int4 B, int4 C, int4 D) {
        *(int4*)(buf + (r0     ) * 1024 + (bc ^ (( r0      & 7) << 4))) = A;
        *(int4*)(buf + (r0 +  4) * 1024 + (bc ^ (((r0 + 4) & 7) << 4))) = B;
        *(int4*)(buf + (r0 +  8) * 1024 + (bc ^ (( r0      & 7) << 4))) = C;
        *(int4*)(buf + (r0 + 12) * 1024 + (bc ^ (((r0 + 4) & 7) << 4))) = D;
    };
    auto xproj0 = [&](int t) {
        const bf16* xp = xb + ((size_t)(b0r + l15) * NT + t) * NDIN + lhi * 8;
        bf16x8 xa0 = *(const bf16x8*)xp;
        bf16x8 xa1 = *(const bf16x8*)(xp + 32);
        aL00 = f32x4{b00, b00, b00, b00};
        aL01 = f32x4{b01, b01, b01, b01};
        aL00 = MFMA16(xa0, asf(wib0[0][0]), aL00); aL00 = MFMA16(xa1, asf(wib0[1][0]), aL00);
        aL01 = MFMA16(xa0, asf(wib0[0][1]), aL01); aL01 = MFMA16(xa1, asf(wib0[1][1]), aL01);
    };
    auto combine = [&](const f32x4& a0, const f32x4& a1, float* cc0, float* cc1,
                       float& h0s, float& h1s) {
        h0s = 0.f; h1s = 0.f;
#pragma unroll
        for (int j = 0; j < 4; ++j) {
            float va = a0[j];
            float gi = __shfl(va, qb), gf = __shfl(va, qb + 1);
            float gc = __shfl(va, qb + 2), go = __shfl(va, qb + 3);
            float cn = fsigm(gf) * cc0[j] + fsigm(gi) * ftanh(gc);
            cc0[j] = cn;
            float h = fsigm(go) * ftanh(cn);
            if (j == g) h0s = h;
            float vb = a1[j];
            gi = __shfl(vb, qb); gf = __shfl(vb, qb + 1);
            gc = __shfl(vb, qb + 2); go = __shfl(vb, qb + 3);
            cn = fsigm(gf) * cc1[j] + fsigm(gi) * ftanh(gc);
            cc1[j] = cn;
            h = fsigm(go) * ftanh(cn);
            if (j == g) h1s = h;
        }
    };
    auto publish = [&](float h0s, float h1s, char* tileBase) {
        u32 pk = pack_bf16(h0s, h1s);
        u32 w0 = __shfl(pk, srcl),     w1 = __shfl(pk, srcl + 4);
        u32 w2 = __shfl(pk, srcl + 8), w3 = __shfl(pk, srcl + 12);
        if (l < 16) {
            char* rp = tileBase + (size_t)l * 1024 + hs * 2 + v * 16;
            union { u32 w[2]; u64 q; } qa, qb2;
            qa.w[0] = w0; qa.w[1] = w1; qb2.w[0] = w2; qb2.w[1] = w3;
            st64_cohr(rp, qa.q); st64_cohr(rp + 8, qb2.q);
        }
    };
    auto setFlag = [&](u32* base, u32 val) {   // per-wave: after own vm_drain only
        if (l < 16) ast32(base + (size_t)l * 64, val);
    };

    __syncthreads();    // WhLds ready

    // ---- epoch 0: layer0 step 0; prefetch ys0[0] tile ----------------------
    xproj0(0);
    {
        float h0s, h1s;
        combine(aL00, aL01, cA0, cA1, h0s, h1s);
        publish(h0s, h1s, y0r + (size_t)b0r * 1024);     // ys0[0] slot 0
        vm_drain();
        setFlag(peerFY, 1u);
        poll64(myLineY + l, 1u);       // all producers' ys0[0] visible
        ld_fence();
        issueG(0);
        vm_drain();                    // G regs = ys0[0]
        xproj0(1);
    }

    // ---- epochs 1..NT ------------------------------------------------------
    for (int e = 1; e <= NT; ++e) {
        const bool doL0 = (e < NT);
        const bool doH1 = (e >= 2);

        // G regs hold ys0[e-1] (prefetched at tail of previous epoch)
        __syncthreads();               // B1: all waves finished prev epoch body
        ldsWrite(hbufY, G0, G1, G2, G3);
        __syncthreads();               // B2: hbufY ready

        // phase-1: layer0-h (wb0) + layer1-x (wib1), shared A-frags from hbufY
        aL10 = f32x4{b10, b10, b10, b10};
        aL11 = f32x4{b11, b11, b11, b11};
#pragma unroll
        for (int kk = 0; kk < 16; ++kk) {
            bf16x8 ha = *(const bf16x8*)(hbufY + l15 * 1024 + ((kk * 64 + lhi * 16) ^ swz));
            if (doL0) {
                aL00 = MFMA16(ha, asf(wb0[kk][0]), aL00);
                aL01 = MFMA16(ha, asf(wb0[kk][1]), aL01);
            }
            aL10 = MFMA16(ha, asf(wib1[kk][0]), aL10);
            aL11 = MFMA16(ha, asf(wib1[kk][1]), aL11);
        }

        // H exchange: poll peers' end-of-(e-1) flags, issue load; RTT hides
        // under combine0+publish below.
        if (doH1) {
            poll64(myLineH + l, (u32)(e - 1));
            ld_fence();
            issueH(e & 1);             // h1[e-2], slot (e-2)&1 == e&1
        }

        if (doL0) {                    // layer0 combine + publish ys0[e]
            float h0s, h1s;
            combine(aL00, aL01, cA0, cA1, h0s, h1s);
            publish(h0s, h1s, y0r + (size_t)(e & 1) * SLOT_BYTES + (size_t)b0r * 1024);
        }
        vm_drain();                    // H load arrived AND ys0[e] stores acked
        if (doL0) setFlag(peerFY, (u32)(e + 1));   // MID-epoch release of ys0[e]

        if (doH1) {                    // phase-2: layer1-h, A=hbufH, B=W_hh1
            ldsWrite(hbufH, H0, H1, H2, H3);
            __syncthreads();           // B3: hbufH ready (prev readers done at B1)
#pragma unroll
            for (int kk = 0; kk < 16; ++kk) {
                int kb = kk * 64 + lhi * 16;
                bf16x8 a  = *(const bf16x8*)(hbufH + l15 * 1024 + (kb ^ swz));
                bf16x8 w0 = *(const bf16x8*)(WhLds + (size_t) lr0      * 1024 + (kb ^ wsw));
                bf16x8 w1 = *(const bf16x8*)(WhLds + (size_t)(lr0 + 1) * 1024 + (kb ^ wsw));
                aL10 = MFMA16(a, w0, aL10);
                aL11 = MFMA16(a, w1, aL11);
            }
        }

        // next-epoch Y prefetch: flagY(e+1) was set mid-epoch by peers;
        // G-load RTT hides under combine1+publish+xproj below.
        if (e < NT) {
            poll64(myLineY + l, (u32)(e + 1));
            ld_fence();
            issueG(e & 1);             // ys0[e], slot e&1
        }

        {                              // layer1 combine + publish h1[e-1]
            float h0s, h1s;
            combine(aL10, aL11, cB0, cB1, h0s, h1s);
            if (e < NT) {
                publish(h0s, h1s, r1 + (size_t)((e - 1) & 1) * SLOT_BYTES + (size_t)b0r * 1024);
                if (e + 1 < NT) xproj0(e + 1);   // hides store+G-load latency
                vm_drain();            // G load arrived AND h1 stores acked
                setFlag(peerFH, (u32)e);         // end-of-epoch release of h1[e-1]
            } else {                   // final hidden state, f32
                float* hp = hT + (size_t)(b0r + lhi * 4 + g) * NH + hs + 8 * v + 2 * csel;
                hp[0] = h0s; hp[1] = h1s;
            }
        }
    }
}

// ---------------------------------------------------------------------------
__global__ __launch_bounds__(256) void fc_kernel(const float* __restrict__ fc1_w,
                                                 const float* __restrict__ fc1_b,
                                                 const float* __restrict__ fc_w,
                                                 const float* __restrict__ fc_b,
                                                 const char* __restrict__ ws,
                                                 float* __restrict__ out) {
    __shared__ float hLds[512];
    __shared__ float red[256];
    const int b = blockIdx.x, tid = threadIdx.x;
    const float* hT = (const float*)(ws + OFF_HT) + (size_t)b * NH;
    hLds[tid]       = hT[tid];
    hLds[tid + 256] = hT[tid + 256];
    __syncthreads();
    float p = 0.f;
#pragma unroll
    for (int rep = 0; rep < 2; ++rep) {
        int hh = tid + rep * 256;
        const float* wr = fc1_w + (size_t)hh * 512;
        float s = fc1_b[hh];
        for (int k = 0; k < 512; k += 4) {
            float4 w4 = *(const float4*)(wr + k);
            s += hLds[k] * w4.x + hLds[k + 1] * w4.y + hLds[k + 2] * w4.z + hLds[k + 3] * w4.w;
        }
        s = fmaxf(s, 0.f);
        p += s * fc_w[hh];
    }
    red[tid] = p;
    __syncthreads();
    for (int off = 128; off > 0; off >>= 1) {
        if (tid < off) red[tid] += red[tid + off];
        __syncthreads();
    }
    if (tid == 0) out[b] = fmaxf(red[0] + fc_b[0], 0.f);
}

// ---------------------------------------------------------------------------
extern "C" void kernel_launch(void* const* d_in, const int* in_sizes, int n_in,
                              void* d_out, int out_size, void* d_ws, size_t ws_size,
                              hipStream_t stream) {
    const float* x    = (const float*)d_in[0];
    const float* Wih0 = (const float*)d_in[1];
    const float* Whh0 = (const float*)d_in[2];
    const float* b0   = (const float*)d_in[3];
    const float* Wih1 = (const float*)d_in[4];
    const float* Whh1 = (const float*)d_in[5];
    const float* b1   = (const float*)d_in[6];
    const float* fc1w = (const float*)d_in[7];
    const float* fc1b = (const float*)d_in[8];
    const float* fcw  = (const float*)d_in[9];
    const float* fcb  = (const float*)d_in[10];
    char* ws = (char*)d_ws;
    float* out = (float*)d_out;

    if (ws_size < WS_NEED) {
        (void)hipMemsetAsync(d_out, 0, (size_t)out_size * 4, stream);
        return;
    }

    // flags must be zero every call (graph replays re-run this)
    (void)hipMemsetAsync(ws + OFF_FLG, 0, 131072, stream);

    hipLaunchKernelGGL(xcvt_kernel, dim3(4096), dim3(256), 0, stream, x, ws);
    hipLaunchKernelGGL(prep_kernel, dim3(4096), dim3(256), 0, stream,
                       Wih0, Whh0, Wih1, Whh1, ws);
    hipLaunchKernelGGL(lstm_fused, dim3(256), dim3(256), 163840, stream, b0, b1, ws);
    hipLaunchKernelGGL(fc_kernel, dim3(256), dim3(256), 0, stream,
                       fc1w, fc1b, fcw, fcb, ws, out);
}

// Round 2
// 3071.340 us; speedup vs baseline: 1.0700x; 1.0700x over previous
//
#include <hip/hip_runtime.h>
#include <stdint.h>

// ---------------------------------------------------------------------------
// 2-layer LSTM (B=256, T=512, D_IN=64, H=512) + FC head, MI355X/gfx950.
// Round 17 = r15 (best, 3030us) + PACKED SHARED FLAG LINES.
//   rocprof r15/r16: WRITE_SIZE ~1.3GB/dispatch, of which ~1.07GB is flag
//   stores (64 stores/WG/epoch, each to its OWN 256B-strided line -> full
//   HBM line write each).  FETCH ~1.1GB = consumers spin-fetching their
//   private 256B poll regions from HBM.  The exchange hop was paying
//   HBM-class latency + queueing on pure flag traffic.
//   Fix: ONE shared 256B flag line per group (64 u32, slot = htile*4+v).
//   - producer wave stores 1 flag (lane 0), not 16  -> write traffic /16
//   - all 16 consumers of a group poll the SAME 2 lines (lane l = slot l)
//     -> poll fetch /16, lines stay hot
//   Protocol values and set points identical to r15 (set e+1 after own
//   vm_drain of both publishes; poll >= e at epoch top) -> r15-proven
//   ordering argument carries over unchanged; only flag ADDRESSES changed.
// Everything else byte-identical to r15 (WG-coop 64B/lane staged loads,
// shuffle-gather publish, 2 barriers/epoch, dual LDS stage buffers).
// ---------------------------------------------------------------------------

typedef __bf16 bf16;
typedef bf16  bf16x8 __attribute__((ext_vector_type(8)));
typedef float f32x4  __attribute__((ext_vector_type(4)));
typedef unsigned int u32;
typedef unsigned long long u64;

#define NB   256
#define NT   512
#define NDIN 64
#define NH   512
#define POLL_GUARD (1 << 20)
#define SLOT_BYTES ((size_t)NB * NH * 2)          // 262144

// workspace layout (bytes)
static constexpr size_t OFF_XB   = 0;                                  // [B][T][64] bf16
static constexpr size_t OFF_WB0  = OFF_XB  + (size_t)NB*NT*NDIN*2;     // Whh0 bf16 [2048][512]
static constexpr size_t OFF_WI0  = OFF_WB0 + (size_t)2048*512*2;       // Wih0 bf16 [2048][64]
static constexpr size_t OFF_WI1  = OFF_WI0 + (size_t)2048*64*2;        // Wih1 bf16 [2048][512]
static constexpr size_t OFF_WHS1 = OFF_WI1 + (size_t)2048*512*2;       // Whh1 swizzled slices
static constexpr size_t OFF_Y0R  = OFF_WHS1+ (size_t)16*128*512*2;     // ys0 ring [2][B][H] bf16
static constexpr size_t OFF_R1   = OFF_Y0R + 2*SLOT_BYTES;             // h1  ring [2][B][H] bf16
static constexpr size_t OFF_HT   = OFF_R1  + 2*SLOT_BYTES;             // [B][H] f32
static constexpr size_t OFF_FLG  = OFF_HT  + (size_t)NB*NH*4;          // u32[16grp][64slot] = 4KB
static constexpr size_t WS_NEED  = OFF_FLG + 4096;

#define MFMA16(a,b,c) __builtin_amdgcn_mfma_f32_16x16x32_bf16(a,b,c,0,0,0)

__device__ __forceinline__ float fsigm(float x) {
    return __builtin_amdgcn_rcpf(1.0f + __builtin_amdgcn_exp2f(x * -1.442695041f));
}
__device__ __forceinline__ float ftanh(float x) {
    return 1.0f - 2.0f * __builtin_amdgcn_rcpf(1.0f + __builtin_amdgcn_exp2f(x * 2.885390082f));
}
__device__ __forceinline__ u32 pack_bf16(float a, float b) {
    union { bf16 h[2]; u32 u; } un;
    un.h[0] = (bf16)a; un.h[1] = (bf16)b;
    return un.u;
}
__device__ __forceinline__ bf16x8 asf(int4 x) {
    union { int4 i; bf16x8 v; } u; u.i = x; return u.v;
}

// --- IC-coherent (sc0 sc1) batched exchange ops [proven r6/r8/r10] ---------
__device__ __forceinline__ void ld4_issue(const void* p0, const void* p1,
                                          const void* p2, const void* p3,
                                          int4& a, int4& b, int4& c, int4& d) {
    asm volatile(
        "global_load_dwordx4 %0, %4, off sc0 sc1\n\t"
        "global_load_dwordx4 %1, %5, off sc0 sc1\n\t"
        "global_load_dwordx4 %2, %6, off sc0 sc1\n\t"
        "global_load_dwordx4 %3, %7, off sc0 sc1"
        : "=&v"(a), "=&v"(b), "=&v"(c), "=&v"(d)
        : "v"(p0), "v"(p1), "v"(p2), "v"(p3)
        : "memory");
}
__device__ __forceinline__ void st64_cohr(void* p, u64 v) {
    asm volatile("global_store_dwordx2 %0, %1, off sc0 sc1" :: "v"(p), "v"(v) : "memory");
}
__device__ __forceinline__ void vm_drain() {      // rule #18: sched fence after waitcnt
    asm volatile("s_waitcnt vmcnt(0)" ::: "memory");
    __builtin_amdgcn_sched_barrier(0);
}
__device__ __forceinline__ void ld_fence() {
    asm volatile("" ::: "memory");
    __builtin_amdgcn_sched_barrier(0);
}
__device__ __forceinline__ void poll64(const u32* f, u32 target) {
    int guard = 0;
    while (__hip_atomic_load(f, __ATOMIC_RELAXED, __HIP_MEMORY_SCOPE_AGENT) < target)
        if (++guard > POLL_GUARD) break;   // wrong answer beats a hard hang
}
__device__ __forceinline__ void ast32(u32* p, u32 v) {
    __hip_atomic_store(p, v, __ATOMIC_RELAXED, __HIP_MEMORY_SCOPE_AGENT);
}

// W_hh1 LDS swizzle slot for local row lr [proven r8/r10]
__device__ __forceinline__ int wslot(int lr) {
    return ((lr >> 5) & 3) | (((lr >> 1) & 3) << 2);
}

// ---------------------------------------------------------------------------
__global__ void xcvt_kernel(const float* __restrict__ x, char* __restrict__ ws) {
    size_t i = ((size_t)blockIdx.x * 256 + threadIdx.x) * 8;
    float4 a = *(const float4*)(x + i);
    float4 b = *(const float4*)(x + i + 4);
    u32 p0 = pack_bf16(a.x, a.y), p1 = pack_bf16(a.z, a.w);
    u32 p2 = pack_bf16(b.x, b.y), p3 = pack_bf16(b.z, b.w);
    *(int4*)(ws + OFF_XB + i * 2) = make_int4((int)p0, (int)p1, (int)p2, (int)p3);
}

__global__ void prep_kernel(const float* __restrict__ Wih0f, const float* __restrict__ Whh0f,
                            const float* __restrict__ Wih1f, const float* __restrict__ Whh1f,
                            char* __restrict__ ws) {
    int idx = blockIdx.x * 256 + threadIdx.x;       // 0 .. 1048575
    ((bf16*)(ws + OFF_WB0))[idx] = (bf16)Whh0f[idx];
    ((bf16*)(ws + OFF_WI1))[idx] = (bf16)Wih1f[idx];
    if (idx < 2048 * 64) ((bf16*)(ws + OFF_WI0))[idx] = (bf16)Wih0f[idx];
    int slice = idx >> 16;
    int lr    = (idx >> 9) & 127;
    int k     = idx & 511;
    int grow  = (lr >> 5) * 512 + slice * 32 + (lr & 31);
    ((bf16*)(ws + OFF_WHS1))[(size_t)slice * 65536 + lr * 512 + (k ^ (wslot(lr) << 3))] =
        (bf16)Whh1f[(size_t)grow * 512 + k];
}

// ---------------------------------------------------------------------------
// fused dual-layer LSTM: r15 structure, packed shared flag lines (r17)
// ---------------------------------------------------------------------------
__global__ __attribute__((amdgpu_waves_per_eu(1, 1))) __launch_bounds__(256)
void lstm_fused(const float* __restrict__ b0, const float* __restrict__ b1,
                char* __restrict__ ws) {
    extern __shared__ char smem[];
    char* WhLds = smem;                // 131072: W_hh1 slice (read-only in loop)
    char* hbufY = smem + 131072;       // 16384: ys0[e-1] tile
    char* hbufH = smem + 147456;       // 16384: h1[e-2] tile

    const int tid = threadIdx.x;
    const int v = tid >> 6, l = tid & 63;
    const int l15 = l & 15, lhi = l >> 4, g = l & 3, csel = l15 >> 2;
    const int group = blockIdx.x >> 4, htile = blockIdx.x & 15;
    const int b0r = group * 16, hs = htile * 32;

    const bf16* xb = (const bf16*)(ws + OFF_XB);
    char* y0r = ws + OFF_Y0R;
    char* r1  = ws + OFF_R1;
    float* hT = (float*)(ws + OFF_HT);
    u32* FL = (u32*)(ws + OFF_FLG);
    // ONE shared 64-slot line per group: slot s written by producer wave
    // (htile = s>>2, v = s&3).  Every consumer of the group polls the same
    // line; lane l polls slot l (covers all 64 producer waves).
    const u32* myLine = FL + (size_t)group * 64;
    u32* peerF        = FL + (size_t)group * 64 + htile * 4 + v;

    // stage pre-swizzled W_hh1 slice -> LDS (written once; read-only in loop)
    {
        const char* wsrc = ws + OFF_WHS1 + (size_t)htile * 131072;
#pragma unroll
        for (int i = 0; i < 32; ++i) {
            int off = (tid + i * 256) * 16;
            *(int4*)(WhLds + off) = *(const int4*)(wsrc + off);
        }
    }

    // lane -> output mapping (r8/r10): col n=l15 -> gate n&3, unit 8v+2*(n>>2)(+1)
    const int wrow0 = g * 512 + hs + 8 * v + 2 * csel;
    const int wrow1 = wrow0 + 1;

    const bf16* wb0p = (const bf16*)(ws + OFF_WB0);
    const bf16* wi0p = (const bf16*)(ws + OFF_WI0);
    const bf16* wi1p = (const bf16*)(ws + OFF_WI1);
    int4 wb0[16][2], wib1[16][2];
#pragma unroll
    for (int kk = 0; kk < 16; ++kk) {
        wb0[kk][0]  = *(const int4*)(wb0p + (size_t)wrow0 * NH + kk * 32 + lhi * 8);
        wb0[kk][1]  = *(const int4*)(wb0p + (size_t)wrow1 * NH + kk * 32 + lhi * 8);
        wib1[kk][0] = *(const int4*)(wi1p + (size_t)wrow0 * NH + kk * 32 + lhi * 8);
        wib1[kk][1] = *(const int4*)(wi1p + (size_t)wrow1 * NH + kk * 32 + lhi * 8);
    }
    int4 wib0[2][2];
#pragma unroll
    for (int kk = 0; kk < 2; ++kk) {
        wib0[kk][0] = *(const int4*)(wi0p + (size_t)wrow0 * NDIN + kk * 32 + lhi * 8);
        wib0[kk][1] = *(const int4*)(wi0p + (size_t)wrow1 * NDIN + kk * 32 + lhi * 8);
    }
    const float b00 = b0[wrow0], b01 = b0[wrow1];
    const float b10 = b1[wrow0], b11 = b1[wrow1];

    float cA0[4] = {0,0,0,0}, cA1[4] = {0,0,0,0};
    float cB0[4] = {0,0,0,0}, cB1[4] = {0,0,0,0};
    f32x4 aL00, aL01, aL10, aL11;
    const int qb = l & 60;
    const int srcl = csel * 16 + g;
    const int swz = (l15 & 7) << 4;
    const int lr0 = g * 32 + 8 * v + 2 * csel;
    const int wsw = wslot(lr0) << 4;
    const int r0 = tid >> 6;
    const int bc = (tid & 63) * 16;

    int4 G0, G1, G2, G3;               // staged ys0 tile
    int4 H0, H1, H2, H3;               // staged h1 tile

    auto issueG = [&](int slot) {
        const char* p = y0r + (size_t)slot * SLOT_BYTES + (size_t)b0r * 1024
                      + (size_t)r0 * 1024 + bc;
        ld4_issue(p, p + 4096, p + 8192, p + 12288, G0, G1, G2, G3);
    };
    auto issueH = [&](int slot) {
        const char* p = r1 + (size_t)slot * SLOT_BYTES + (size_t)b0r * 1024
                      + (size_t)r0 * 1024 + bc;
        ld4_issue(p, p + 4096, p + 8192, p + 12288, H0, H1, H2, H3);
    };
    auto ldsWrite = [&](char* buf, int4 A, int4 B, int4 C, int4 D) {
        *(int4*)(buf + (r0     ) * 1024 + (bc ^ (( r0      & 7) << 4))) = A;
        *(int4*)(buf + (r0 +  4) * 1024 + (bc ^ (((r0 + 4) & 7) << 4))) = B;
        *(int4*)(buf + (r0 +  8) * 1024 + (bc ^ (( r0      & 7) << 4))) = C;
        *(int4*)(buf + (r0 + 12) * 1024 + (bc ^ (((r0 + 4) & 7) << 4))) = D;
    };
    auto xproj0 = [&](int t) {
        const bf16* xp = xb + ((size_t)(b0r + l15) * NT + t) * NDIN + lhi * 8;
        bf16x8 xa0 = *(const bf16x8*)xp;
        bf16x8 xa1 = *(const bf16x8*)(xp + 32);
        aL00 = f32x4{b00, b00, b00, b00};
        aL01 = f32x4{b01, b01, b01, b01};
        aL00 = MFMA16(xa0, asf(wib0[0][0]), aL00); aL00 = MFMA16(xa1, asf(wib0[1][0]), aL00);
        aL01 = MFMA16(xa0, asf(wib0[0][1]), aL01); aL01 = MFMA16(xa1, asf(wib0[1][1]), aL01);
    };
    auto combine = [&](const f32x4& a0, const f32x4& a1, float* cc0, float* cc1,
                       float& h0s, float& h1s) {
        h0s = 0.f; h1s = 0.f;
#pragma unroll
        for (int j = 0; j < 4; ++j) {
            float va = a0[j];
            float gi = __shfl(va, qb), gf = __shfl(va, qb + 1);
            float gc = __shfl(va, qb + 2), go = __shfl(va, qb + 3);
            float cn = fsigm(gf) * cc0[j] + fsigm(gi) * ftanh(gc);
            cc0[j] = cn;
            float h = fsigm(go) * ftanh(cn);
            if (j == g) h0s = h;
            float vb = a1[j];
            gi = __shfl(vb, qb); gf = __shfl(vb, qb + 1);
            gc = __shfl(vb, qb + 2); go = __shfl(vb, qb + 3);
            cn = fsigm(gf) * cc1[j] + fsigm(gi) * ftanh(gc);
            cc1[j] = cn;
            h = fsigm(go) * ftanh(cn);
            if (j == g) h1s = h;
        }
    };
    auto publish = [&](float h0s, float h1s, char* tileBase) {
        u32 pk = pack_bf16(h0s, h1s);
        u32 w0 = __shfl(pk, srcl),     w1 = __shfl(pk, srcl + 4);
        u32 w2 = __shfl(pk, srcl + 8), w3 = __shfl(pk, srcl + 12);
        if (l < 16) {
            char* rp = tileBase + (size_t)l * 1024 + hs * 2 + v * 16;
            union { u32 w[2]; u64 q; } qa, qb2;
            qa.w[0] = w0; qa.w[1] = w1; qb2.w[0] = w2; qb2.w[1] = w3;
            st64_cohr(rp, qa.q); st64_cohr(rp + 8, qb2.q);
        }
    };
    auto setF = [&](u32 val) {     // per-wave: after own vm_drain only; 1 store
        if (l == 0) ast32(peerF, val);
    };

    __syncthreads();    // WhLds ready

    // ---- epoch 0: layer0 step 0 only --------------------------------------
    xproj0(0);
    {
        float h0s, h1s;
        combine(aL00, aL01, cA0, cA1, h0s, h1s);
        publish(h0s, h1s, y0r + (size_t)b0r * 1024);     // ys0[0] slot 0
        vm_drain();
        setF(1u);
        xproj0(1);
    }

    // ---- epochs 1..NT ------------------------------------------------------
    for (int e = 1; e <= NT; ++e) {
        const bool doL0 = (e < NT);
        const bool doH1 = (e >= 2);

        poll64(myLine + l, (u32)e);    // single poll point (r10-style)
        ld_fence();
        issueG((e - 1) & 1);
        if (doH1) issueH(e & 1);
        vm_drain();

        __syncthreads();               // B1: prev epoch's hbuf readers done
        ldsWrite(hbufY, G0, G1, G2, G3);
        if (doH1) ldsWrite(hbufH, H0, H1, H2, H3);
        __syncthreads();               // B2: both tiles ready

        // phase-1: layer0-h (wb0) + layer1-x (wib1), shared A-frags from hbufY
        aL10 = f32x4{b10, b10, b10, b10};
        aL11 = f32x4{b11, b11, b11, b11};
#pragma unroll
        for (int kk = 0; kk < 16; ++kk) {
            bf16x8 ha = *(const bf16x8*)(hbufY + l15 * 1024 + ((kk * 64 + lhi * 16) ^ swz));
            if (doL0) {
                aL00 = MFMA16(ha, asf(wb0[kk][0]), aL00);
                aL01 = MFMA16(ha, asf(wb0[kk][1]), aL01);
            }
            aL10 = MFMA16(ha, asf(wib1[kk][0]), aL10);
            aL11 = MFMA16(ha, asf(wib1[kk][1]), aL11);
        }

        if (doL0) {                    // layer0 combine + publish (no drain yet:
            float h0s, h1s;            //  store latency hides under phase-2)
            combine(aL00, aL01, cA0, cA1, h0s, h1s);
            publish(h0s, h1s, y0r + (size_t)(e & 1) * SLOT_BYTES + (size_t)b0r * 1024);
        }

        if (doH1) {                    // phase-2: layer1-h, A=hbufH, B=W_hh1
#pragma unroll
            for (int kk = 0; kk < 16; ++kk) {
                int kb = kk * 64 + lhi * 16;
                bf16x8 a  = *(const bf16x8*)(hbufH + l15 * 1024 + (kb ^ swz));
                bf16x8 w0 = *(const bf16x8*)(WhLds + (size_t) lr0      * 1024 + (kb ^ wsw));
                bf16x8 w1 = *(const bf16x8*)(WhLds + (size_t)(lr0 + 1) * 1024 + (kb ^ wsw));
                aL10 = MFMA16(a, w0, aL10);
                aL11 = MFMA16(a, w1, aL11);
            }
        }

        {                              // layer1 combine + publish h1(e-1)
            float h0s, h1s;
            combine(aL10, aL11, cB0, cB1, h0s, h1s);
            if (e < NT) {
                publish(h0s, h1s, r1 + (size_t)((e - 1) & 1) * SLOT_BYTES + (size_t)b0r * 1024);
            } else {                   // final hidden state, f32
                float* hp = hT + (size_t)(b0r + lhi * 4 + g) * NH + hs + 8 * v + 2 * csel;
                hp[0] = h0s; hp[1] = h1s;
            }
        }
        if (e < NT) {
            vm_drain();                // both publishes acked at IC
            setF((u32)(e + 1));        // per-wave flag, 1 store/wave
            xproj0(e + 1);             // next layer0 x-proj under peers' skew
        }
    }
}

// ---------------------------------------------------------------------------
__global__ __launch_bounds__(256) void fc_kernel(const float* __restrict__ fc1_w,
                                                 const float* __restrict__ fc1_b,
                                                 const float* __restrict__ fc_w,
                                                 const float* __restrict__ fc_b,
                                                 const char* __restrict__ ws,
                                                 float* __restrict__ out) {
    __shared__ float hLds[512];
    __shared__ float red[256];
    const int b = blockIdx.x, tid = threadIdx.x;
    const float* hT = (const float*)(ws + OFF_HT) + (size_t)b * NH;
    hLds[tid]       = hT[tid];
    hLds[tid + 256] = hT[tid + 256];
    __syncthreads();
    float p = 0.f;
#pragma unroll
    for (int rep = 0; rep < 2; ++rep) {
        int hh = tid + rep * 256;
        const float* wr = fc1_w + (size_t)hh * 512;
        float s = fc1_b[hh];
        for (int k = 0; k < 512; k += 4) {
            float4 w4 = *(const float4*)(wr + k);
            s += hLds[k] * w4.x + hLds[k + 1] * w4.y + hLds[k + 2] * w4.z + hLds[k + 3] * w4.w;
        }
        s = fmaxf(s, 0.f);
        p += s * fc_w[hh];
    }
    red[tid] = p;
    __syncthreads();
    for (int off = 128; off > 0; off >>= 1) {
        if (tid < off) red[tid] += red[tid + off];
        __syncthreads();
    }
    if (tid == 0) out[b] = fmaxf(red[0] + fc_b[0], 0.f);
}

// ---------------------------------------------------------------------------
extern "C" void kernel_launch(void* const* d_in, const int* in_sizes, int n_in,
                              void* d_out, int out_size, void* d_ws, size_t ws_size,
                              hipStream_t stream) {
    const float* x    = (const float*)d_in[0];
    const float* Wih0 = (const float*)d_in[1];
    const float* Whh0 = (const float*)d_in[2];
    const float* b0   = (const float*)d_in[3];
    const float* Wih1 = (const float*)d_in[4];
    const float* Whh1 = (const float*)d_in[5];
    const float* b1   = (const float*)d_in[6];
    const float* fc1w = (const float*)d_in[7];
    const float* fc1b = (const float*)d_in[8];
    const float* fcw  = (const float*)d_in[9];
    const float* fcb  = (const float*)d_in[10];
    char* ws = (char*)d_ws;
    float* out = (float*)d_out;

    if (ws_size < WS_NEED) {
        (void)hipMemsetAsync(d_out, 0, (size_t)out_size * 4, stream);
        return;
    }

    // flags must be zero every call (graph replays re-run this)
    (void)hipMemsetAsync(ws + OFF_FLG, 0, 4096, stream);

    hipLaunchKernelGGL(xcvt_kernel, dim3(4096), dim3(256), 0, stream, x, ws);
    hipLaunchKernelGGL(prep_kernel, dim3(4096), dim3(256), 0, stream,
                       Wih0, Whh0, Wih1, Whh1, ws);
    hipLaunchKernelGGL(lstm_fused, dim3(256), dim3(256), 163840, stream, b0, b1, ws);
    hipLaunchKernelGGL(fc_kernel, dim3(256), dim3(256), 0, stream,
                       fc1w, fc1b, fcw, fcb, ws, out);
}